// Round 2
// baseline (2061.956 us; speedup 1.0000x reference)
//
#include <hip/hip_runtime.h>

#define BB 8
#define NN 1024
#define CC 768
#define OO 768
#define RR 16
#define MM (BB*NN)      /* 8192  */
#define KK (CC*RR)      /* 12288 */
#define BM 128
#define BO 96
#define BK 64
#define KTILES (KK/BK)  /* 192 */
#define MTILES (MM/BM)  /* 64  */
#define OTILES (OO/BO)  /* 8   */
#define NBLK (MTILES*OTILES) /* 512 = 2 blocks/CU exactly */
#define NTHR 384        /* 6 waves: 2(m) x 3(o), wave tile 64m x 32o */

typedef __bf16 bf16x8 __attribute__((ext_vector_type(8)));
typedef float  f32x4  __attribute__((ext_vector_type(4)));
typedef float  f32x2  __attribute__((ext_vector_type(2)));

__device__ static __forceinline__ void gl_lds16(const void* g, void* l) {
    __builtin_amdgcn_global_load_lds(
        (const __attribute__((address_space(1))) void*)g,
        (__attribute__((address_space(3))) void*)l,
        16, 0, 0);
}

__device__ static __forceinline__ f32x2 mk2(float a, float b) {
    f32x2 v; v[0] = a; v[1] = b; return v;
}

// ---- prep: weight fp32 -> bf16 (ws), and bias_term[n,o] = coef[n,:]·bias[o,:] ----
__global__ __launch_bounds__(256) void k_prep(const float* __restrict__ w,
                                              const float* __restrict__ coef,
                                              const float* __restrict__ bias,
                                              __bf16* __restrict__ wbf,
                                              float* __restrict__ bterm) {
    long id = blockIdx.x;
    if (id < 4608) {                       // convert 9.44M weights, 8/thread
        long u = (id * 256 + threadIdx.x) * 8;
        float4 a = *(const float4*)(w + u);
        float4 b = *(const float4*)(w + u + 4);
        bf16x8 v = {(__bf16)a.x, (__bf16)a.y, (__bf16)a.z, (__bf16)a.w,
                    (__bf16)b.x, (__bf16)b.y, (__bf16)b.z, (__bf16)b.w};
        *(bf16x8*)(wbf + u) = v;
    } else {                               // bias_term: 1024*768 dots of length 16
        int i = (int)(id - 4608) * 256 + threadIdx.x;
        int n = i / OO, o = i - n * OO;
        float4 c0 = *(const float4*)(coef + n * RR);
        float4 c1 = *(const float4*)(coef + n * RR + 4);
        float4 c2 = *(const float4*)(coef + n * RR + 8);
        float4 c3 = *(const float4*)(coef + n * RR + 12);
        float4 b0 = *(const float4*)(bias + o * RR);
        float4 b1 = *(const float4*)(bias + o * RR + 4);
        float4 b2 = *(const float4*)(bias + o * RR + 8);
        float4 b3 = *(const float4*)(bias + o * RR + 12);
        float s = c0.x*b0.x + c0.y*b0.y + c0.z*b0.z + c0.w*b0.w
                + c1.x*b1.x + c1.y*b1.y + c1.z*b1.z + c1.w*b1.w
                + c2.x*b2.x + c2.y*b2.y + c2.z*b2.z + c2.w*b2.w
                + c3.x*b3.x + c3.y*b3.y + c3.z*b3.z + c3.w*b3.w;
        bterm[i] = s;
    }
}

// ---- main GEMM: out[m,o] = sum_k A[m,k]*W[o,k] + bterm[n,o] ----
// A[m, c*16+r] = x[m,c]*coef[n,r] is synthesized IN REGISTERS per MFMA fragment:
// for 16x16x32 bf16 A-layout (row=lane&15, k=(lane>>4)*8+j), lane's fragment is
//   x[row][4kt + 2ks + (quad>>1)] * coef[n(row)][(quad&1)*8 + j]
// -> zero LDS traffic for A. LDS holds only the B (weight) tile, double-buffered.
__global__ __launch_bounds__(NTHR, 3) void k_gemm(const float* __restrict__ x,
                                                  const float* __restrict__ coef,
                                                  const __bf16* __restrict__ wbf,
                                                  const float* __restrict__ bterm,
                                                  float* __restrict__ out) {
    __shared__ __bf16 lB[2][BO * BK];   // 2 x 12 KB

    const int tid = threadIdx.x;

    // XCD swizzle: otile == XCD id -> each XCD reads ONE 96-col W panel (2.4MB < 4MB L2)
    int bid = blockIdx.x;
    int swz = (bid & 7) * (NBLK / 8) + (bid >> 3);
    const int otile = swz >> 6;      // 0..7
    const int mtile = swz & 63;      // 0..63
    const int m0 = mtile * BM, o0 = otile * BO;

    const int lane = tid & 63, wave = tid >> 6;
    const int wr = wave & 1, wc = wave >> 1;        // 2m x 3o waves
    const int lrow = lane & 15, quad = lane >> 4;
    const int q = quad >> 1, rh = quad & 1;

    // ---- per-lane A state: 4 row-blocks (im), 8 coef values each, x row pointers ----
    const float* xp[4];
    f32x2 cfv[4][4];
#pragma unroll
    for (int im = 0; im < 4; ++im) {
        int mg = m0 + wr * 64 + im * 16 + lrow;
        int n  = mg & (NN - 1);
        xp[im] = x + (long)mg * CC;
        float4 a = *(const float4*)(coef + n * RR + rh * 8);
        float4 b = *(const float4*)(coef + n * RR + rh * 8 + 4);
        cfv[im][0] = mk2(a.x, a.y); cfv[im][1] = mk2(a.z, a.w);
        cfv[im][2] = mk2(b.x, b.y); cfv[im][3] = mk2(b.z, b.w);
    }

    f32x4 acc[4][2] = {};

    // stage B-tile kt into buffer b (async DMA, global-side XOR swizzle; 768 chunks)
    auto STAGE = [&](int b, int kt) {
#pragma unroll
        for (int s = 0; s < 2; ++s) {
            int u = s * NTHR + tid;
            int row = u >> 3, cl = u & 7;
            int g = cl ^ (row & 7);
            const __bf16* gp = wbf + (long)(o0 + row) * KK + kt * BK + g * 8;
            gl_lds16(gp, ((char*)lB[b]) + u * 16);
        }
    };

    // ---- prologue ----
    float4 xc[4], xn[4];
#pragma unroll
    for (int im = 0; im < 4; ++im) xc[im] = *(const float4*)(xp[im]);          // kt 0
    STAGE(0, 0);
#pragma unroll
    for (int im = 0; im < 4; ++im) xn[im] = *(const float4*)(xp[im] + 4);      // kt 1
    __syncthreads();

#pragma unroll 2
    for (int kt = 0; kt < KTILES; ++kt) {
        const int cur = kt & 1;
        if (kt + 1 < KTILES) STAGE(cur ^ 1, kt + 1);   // DMA overlaps compute, drained
                                                       // at end-of-iter barrier
        float4 xf[4];
        if (kt + 2 < KTILES) {
#pragma unroll
            for (int im = 0; im < 4; ++im) xf[im] = *(const float4*)(xp[im] + (kt + 2) * 4);
        }

        // ---- compute tile kt: 2 k-steps; A built in regs, B from LDS ----
#pragma unroll
        for (int ks = 0; ks < 2; ++ks) {
            int kb = ks * 4 + quad;
            bf16x8 bfr[2];
#pragma unroll
            for (int io = 0; io < 2; ++io) {
                int row = wc * 32 + io * 16 + lrow;
                bfr[io] = *(const bf16x8*)(&lB[cur][row * BK + (kb ^ (row & 7)) * 8]);
            }
#pragma unroll
            for (int im = 0; im < 4; ++im) {
                float xv = xc[im][ks * 2 + q];
                f32x2 xv2 = mk2(xv, xv);
                bf16x8 af;
#pragma unroll
                for (int h = 0; h < 4; ++h) {
                    f32x2 p = xv2 * cfv[im][h];     // v_pk_mul_f32
                    af[2 * h]     = (__bf16)p[0];
                    af[2 * h + 1] = (__bf16)p[1];
                }
#pragma unroll
                for (int io = 0; io < 2; ++io)
                    acc[im][io] = __builtin_amdgcn_mfma_f32_16x16x32_bf16(
                        af, bfr[io], acc[im][io], 0, 0, 0);
            }
        }

        // rotate x prefetch buffers
#pragma unroll
        for (int im = 0; im < 4; ++im) xc[im] = xn[im];
        if (kt + 2 < KTILES) {
#pragma unroll
            for (int im = 0; im < 4; ++im) xn[im] = xf[im];
        }
        __syncthreads();   // single barrier/iter: drains next-tile DMA, protects buffers
    }

    // ---- epilogue: D col=lane&15 (o), row=quad*4+reg (m); add bias_term ----
#pragma unroll
    for (int im = 0; im < 4; ++im) {
#pragma unroll
        for (int io = 0; io < 2; ++io) {
            int o = o0 + wc * 32 + io * 16 + lrow;
#pragma unroll
            for (int r = 0; r < 4; ++r) {
                int moff = wr * 64 + im * 16 + quad * 4 + r;
                long m = m0 + moff;
                int n = (int)(m & (NN - 1));
                out[m * OO + o] = acc[im][io][r] + bterm[(long)n * OO + o];
            }
        }
    }
}

// ---- fallback if workspace too small (correctness-only) ----
__global__ void k_naive(const float* __restrict__ x, const float* __restrict__ coef,
                        const float* __restrict__ w, const float* __restrict__ bias,
                        float* __restrict__ out) {
    long i = (long)blockIdx.x * 256 + threadIdx.x;
    if (i >= (long)MM * OO) return;
    int o = (int)(i % OO);
    long m = i / OO;
    int n = (int)(m & (NN - 1));
    float cf[16];
#pragma unroll
    for (int r = 0; r < 16; ++r) cf[r] = coef[n * RR + r];
    const float* xr = x + m * CC;
    const float* wr = w + (long)o * CC * RR;
    float s = 0.f;
    for (int c = 0; c < CC; ++c) {
        float t = 0.f;
#pragma unroll
        for (int r = 0; r < 16; ++r) t += cf[r] * wr[c * RR + r];
        s += xr[c] * t;
    }
    float bs = 0.f;
#pragma unroll
    for (int r = 0; r < 16; ++r) bs += cf[r] * bias[o * RR + r];
    out[i] = s + bs;
}

extern "C" void kernel_launch(void* const* d_in, const int* in_sizes, int n_in,
                              void* d_out, int out_size, void* d_ws, size_t ws_size,
                              hipStream_t stream) {
    const float* x    = (const float*)d_in[0];
    const float* coef = (const float*)d_in[1];
    const float* w    = (const float*)d_in[2];
    const float* bias = (const float*)d_in[3];
    float* out = (float*)d_out;

    const size_t wbf_bytes = (size_t)OO * KK * sizeof(__bf16);   // 18,874,368
    const size_t bt_bytes  = (size_t)NN * OO * sizeof(float);    //  3,145,728

    if (ws_size >= wbf_bytes + bt_bytes) {
        __bf16* wbf  = (__bf16*)d_ws;
        float*  btrm = (float*)((char*)d_ws + wbf_bytes);
        k_prep<<<7680, 256, 0, stream>>>(w, coef, bias, wbf, btrm);
        k_gemm<<<NBLK, NTHR, 0, stream>>>(x, coef, wbf, btrm, out);
    } else {
        k_naive<<<(int)(((long)MM * OO + 255) / 256), 256, 0, stream>>>(x, coef, w, bias, out);
    }
}

// Round 3
// 648.870 us; speedup vs baseline: 3.1778x; 3.1778x over previous
//
#include <hip/hip_runtime.h>

#define BB 8
#define NN 1024
#define CC 768
#define OO 768
#define RR 16
#define MM (BB*NN)      /* 8192  */
#define KK (CC*RR)      /* 12288 */
#define BM 128
#define BO 96
#define BK 64
#define KTILES (KK/BK)  /* 192 */
#define MTILES (MM/BM)  /* 64  */
#define OTILES (OO/BO)  /* 8   */
#define NBLK (MTILES*OTILES) /* 512 = 2 blocks/CU exactly */
#define NTHR 384        /* 6 waves: 2(m) x 3(o), wave tile 64m x 32o */

typedef __bf16 bf16x8 __attribute__((ext_vector_type(8)));
typedef float  f32x4  __attribute__((ext_vector_type(4)));
typedef float  f32x2  __attribute__((ext_vector_type(2)));

__device__ static __forceinline__ void gl_lds16(const void* g, void* l) {
    __builtin_amdgcn_global_load_lds(
        (const __attribute__((address_space(1))) void*)g,
        (__attribute__((address_space(3))) void*)l,
        16, 0, 0);
}

__device__ static __forceinline__ f32x2 mk2(float a, float b) {
    f32x2 v; v[0] = a; v[1] = b; return v;
}

// ---- prep: weight fp32 -> bf16 (ws), and bias_term[n,o] = coef[n,:]·bias[o,:] ----
__global__ __launch_bounds__(256) void k_prep(const float* __restrict__ w,
                                              const float* __restrict__ coef,
                                              const float* __restrict__ bias,
                                              __bf16* __restrict__ wbf,
                                              float* __restrict__ bterm) {
    long id = blockIdx.x;
    if (id < 4608) {                       // convert 9.44M weights, 8/thread
        long u = (id * 256 + threadIdx.x) * 8;
        float4 a = *(const float4*)(w + u);
        float4 b = *(const float4*)(w + u + 4);
        bf16x8 v = {(__bf16)a.x, (__bf16)a.y, (__bf16)a.z, (__bf16)a.w,
                    (__bf16)b.x, (__bf16)b.y, (__bf16)b.z, (__bf16)b.w};
        *(bf16x8*)(wbf + u) = v;
    } else {                               // bias_term: 1024*768 dots of length 16
        int i = (int)(id - 4608) * 256 + threadIdx.x;
        int n = i / OO, o = i - n * OO;
        float4 c0 = *(const float4*)(coef + n * RR);
        float4 c1 = *(const float4*)(coef + n * RR + 4);
        float4 c2 = *(const float4*)(coef + n * RR + 8);
        float4 c3 = *(const float4*)(coef + n * RR + 12);
        float4 b0 = *(const float4*)(bias + o * RR);
        float4 b1 = *(const float4*)(bias + o * RR + 4);
        float4 b2 = *(const float4*)(bias + o * RR + 8);
        float4 b3 = *(const float4*)(bias + o * RR + 12);
        float s = c0.x*b0.x + c0.y*b0.y + c0.z*b0.z + c0.w*b0.w
                + c1.x*b1.x + c1.y*b1.y + c1.z*b1.z + c1.w*b1.w
                + c2.x*b2.x + c2.y*b2.y + c2.z*b2.z + c2.w*b2.w
                + c3.x*b3.x + c3.y*b3.y + c3.z*b3.z + c3.w*b3.w;
        bterm[i] = s;
    }
}

// ---- main GEMM: out[m,o] = sum_k A[m,k]*W[o,k] + bterm[n,o] ----
// A[m, c*16+r] = x[m,c]*coef[n,r] is synthesized IN REGISTERS per MFMA fragment:
// for 16x16x32 bf16 A-layout (row=lane&15, k=(lane>>4)*8+j), lane's fragment is
//   x[row][4kt + 2ks + (quad>>1)] * coef[n(row)][(quad&1)*8 + j]
// -> zero LDS traffic for A. LDS holds only the B (weight) tile, double-buffered.
// NOTE (rule #20): x per-tile state is kept as SCALARS extracted with
// compile-time float4 element accesses (cndmask on q) — runtime-indexed
// float4 state sent 10.5 GB/dispatch through scratch in the previous rev.
__global__ __launch_bounds__(NTHR, 3) void k_gemm(const float* __restrict__ x,
                                                  const float* __restrict__ coef,
                                                  const __bf16* __restrict__ wbf,
                                                  const float* __restrict__ bterm,
                                                  float* __restrict__ out) {
    __shared__ __bf16 lB[2][BO * BK];   // 2 x 12 KB

    const int tid = threadIdx.x;

    // XCD swizzle: otile == XCD id -> each XCD reads ONE 96-col W panel (2.4MB < 4MB L2)
    int bid = blockIdx.x;
    int swz = (bid & 7) * (NBLK / 8) + (bid >> 3);
    const int otile = swz >> 6;      // 0..7
    const int mtile = swz & 63;      // 0..63
    const int m0 = mtile * BM, o0 = otile * BO;

    const int lane = tid & 63, wave = tid >> 6;
    const int wr = wave & 1, wc = wave >> 1;        // 2m x 3o waves
    const int lrow = lane & 15, quad = lane >> 4;
    const int q = quad >> 1, rh = quad & 1;

    // ---- per-lane A state: 4 row-blocks (im), 8 coef values each, x row pointers ----
    const float* xp[4];
    f32x2 cfv[4][4];
#pragma unroll
    for (int im = 0; im < 4; ++im) {
        int mg = m0 + wr * 64 + im * 16 + lrow;
        int n  = mg & (NN - 1);
        xp[im] = x + (long)mg * CC;
        float4 a = *(const float4*)(coef + n * RR + rh * 8);
        float4 b = *(const float4*)(coef + n * RR + rh * 8 + 4);
        cfv[im][0] = mk2(a.x, a.y); cfv[im][1] = mk2(a.z, a.w);
        cfv[im][2] = mk2(b.x, b.y); cfv[im][3] = mk2(b.z, b.w);
    }

    f32x4 acc[4][2] = {};

    // stage B-tile kt into buffer b (async DMA, global-side XOR swizzle; 768 chunks)
    auto STAGE = [&](int b, int kt) {
#pragma unroll
        for (int s = 0; s < 2; ++s) {
            int u = s * NTHR + tid;
            int row = u >> 3, cl = u & 7;
            int g = cl ^ (row & 7);
            const __bf16* gp = wbf + (long)(o0 + row) * KK + kt * BK + g * 8;
            gl_lds16(gp, ((char*)lB[b]) + u * 16);
        }
    };

    // ---- prologue: x state as scalars (elements q and 2+q of each float4) ----
    float xc0[4], xc1[4], xn0[4], xn1[4];
#pragma unroll
    for (int im = 0; im < 4; ++im) {
        float4 v = *(const float4*)(xp[im]);                 // kt 0
        xc0[im] = q ? v.y : v.x;
        xc1[im] = q ? v.w : v.z;
    }
    STAGE(0, 0);
#pragma unroll
    for (int im = 0; im < 4; ++im) {
        float4 v = *(const float4*)(xp[im] + 4);             // kt 1
        xn0[im] = q ? v.y : v.x;
        xn1[im] = q ? v.w : v.z;
    }
    __syncthreads();

#pragma unroll 2
    for (int kt = 0; kt < KTILES; ++kt) {
        const int cur = kt & 1;
        if (kt + 1 < KTILES) STAGE(cur ^ 1, kt + 1);   // DMA overlaps compute, drained
                                                       // at end-of-iter barrier
        float xf0[4], xf1[4];
        if (kt + 2 < KTILES) {
#pragma unroll
            for (int im = 0; im < 4; ++im) {
                float4 v = *(const float4*)(xp[im] + (kt + 2) * 4);
                xf0[im] = q ? v.y : v.x;
                xf1[im] = q ? v.w : v.z;
            }
        }

        // ---- compute tile kt: 2 k-steps; A built in regs, B from LDS ----
#pragma unroll
        for (int ks = 0; ks < 2; ++ks) {
            int kb = ks * 4 + quad;
            bf16x8 bfr[2];
#pragma unroll
            for (int io = 0; io < 2; ++io) {
                int row = wc * 32 + io * 16 + lrow;
                bfr[io] = *(const bf16x8*)(&lB[cur][row * BK + (kb ^ (row & 7)) * 8]);
            }
#pragma unroll
            for (int im = 0; im < 4; ++im) {
                float xv = ks ? xc1[im] : xc0[im];
                f32x2 xv2 = mk2(xv, xv);
                bf16x8 af;
#pragma unroll
                for (int h = 0; h < 4; ++h) {
                    f32x2 p = xv2 * cfv[im][h];     // v_pk_mul_f32
                    af[2 * h]     = (__bf16)p[0];
                    af[2 * h + 1] = (__bf16)p[1];
                }
#pragma unroll
                for (int io = 0; io < 2; ++io)
                    acc[im][io] = __builtin_amdgcn_mfma_f32_16x16x32_bf16(
                        af, bfr[io], acc[im][io], 0, 0, 0);
            }
        }

        // rotate x prefetch state (all scalar, compile-time indexed)
#pragma unroll
        for (int im = 0; im < 4; ++im) { xc0[im] = xn0[im]; xc1[im] = xn1[im]; }
        if (kt + 2 < KTILES) {
#pragma unroll
            for (int im = 0; im < 4; ++im) { xn0[im] = xf0[im]; xn1[im] = xf1[im]; }
        }
        __syncthreads();   // single barrier/iter: drains next-tile DMA, protects buffers
    }

    // ---- epilogue: D col=lane&15 (o), row=quad*4+reg (m); add bias_term ----
#pragma unroll
    for (int im = 0; im < 4; ++im) {
#pragma unroll
        for (int io = 0; io < 2; ++io) {
            int o = o0 + wc * 32 + io * 16 + lrow;
#pragma unroll
            for (int r = 0; r < 4; ++r) {
                int moff = wr * 64 + im * 16 + quad * 4 + r;
                long m = m0 + moff;
                int n = (int)(m & (NN - 1));
                out[m * OO + o] = acc[im][io][r] + bterm[(long)n * OO + o];
            }
        }
    }
}

// ---- fallback if workspace too small (correctness-only) ----
__global__ void k_naive(const float* __restrict__ x, const float* __restrict__ coef,
                        const float* __restrict__ w, const float* __restrict__ bias,
                        float* __restrict__ out) {
    long i = (long)blockIdx.x * 256 + threadIdx.x;
    if (i >= (long)MM * OO) return;
    int o = (int)(i % OO);
    long m = i / OO;
    int n = (int)(m & (NN - 1));
    float cf[16];
#pragma unroll
    for (int r = 0; r < 16; ++r) cf[r] = coef[n * RR + r];
    const float* xr = x + m * CC;
    const float* wr = w + (long)o * CC * RR;
    float s = 0.f;
    for (int c = 0; c < CC; ++c) {
        float t = 0.f;
#pragma unroll
        for (int r = 0; r < 16; ++r) t += cf[r] * wr[c * RR + r];
        s += xr[c] * t;
    }
    float bs = 0.f;
#pragma unroll
    for (int r = 0; r < 16; ++r) bs += cf[r] * bias[o * RR + r];
    out[i] = s + bs;
}

extern "C" void kernel_launch(void* const* d_in, const int* in_sizes, int n_in,
                              void* d_out, int out_size, void* d_ws, size_t ws_size,
                              hipStream_t stream) {
    const float* x    = (const float*)d_in[0];
    const float* coef = (const float*)d_in[1];
    const float* w    = (const float*)d_in[2];
    const float* bias = (const float*)d_in[3];
    float* out = (float*)d_out;

    const size_t wbf_bytes = (size_t)OO * KK * sizeof(__bf16);   // 18,874,368
    const size_t bt_bytes  = (size_t)NN * OO * sizeof(float);    //  3,145,728

    if (ws_size >= wbf_bytes + bt_bytes) {
        __bf16* wbf  = (__bf16*)d_ws;
        float*  btrm = (float*)((char*)d_ws + wbf_bytes);
        k_prep<<<7680, 256, 0, stream>>>(w, coef, bias, wbf, btrm);
        k_gemm<<<NBLK, NTHR, 0, stream>>>(x, coef, wbf, btrm, out);
    } else {
        k_naive<<<(int)(((long)MM * OO + 255) / 256), 256, 0, stream>>>(x, coef, w, bias, out);
    }
}

// Round 4
// 373.317 us; speedup vs baseline: 5.5233x; 1.7381x over previous
//
#include <hip/hip_runtime.h>

#define BB 8
#define NN 1024
#define CC 768
#define OO 768
#define RR 16
#define MM (BB*NN)      /* 8192  */
#define KK (CC*RR)      /* 12288 */
#define BM 128
#define BO 192
#define BK 64
#define RBLK 16         /* r values (k-tile groups sharing one x-chunk) */
#define CBLK 12         /* 64-wide c-chunks */
#define MTILES (MM/BM)  /* 64 */
#define OTILES (OO/BO)  /* 4  */
#define NBLK (MTILES*OTILES) /* 256 = exactly 1 block/CU */
#define NTHR 768        /* 12 waves: 4(m) x 3(o); wave tile 32m x 64o */

typedef __bf16 bf16x8 __attribute__((ext_vector_type(8)));
typedef float  f32x4  __attribute__((ext_vector_type(4)));
typedef float  f32x2  __attribute__((ext_vector_type(2)));

__device__ static __forceinline__ void gl_lds16(const void* g, void* l) {
    __builtin_amdgcn_global_load_lds(
        (const __attribute__((address_space(1))) void*)g,
        (__attribute__((address_space(3))) void*)l,
        16, 0, 0);
}

__device__ static __forceinline__ f32x2 mk2(float a, float b) {
    f32x2 v; v[0] = a; v[1] = b; return v;
}

// ---- prep: weight fp32 -> bf16 in R-MAJOR-K layout wbf[o][r*768+c] = w[o][c][r],
//      and bias_term[n,o] = coef[n,:]·bias[o,:] ----
__global__ __launch_bounds__(256) void k_prep(const float* __restrict__ w,
                                              const float* __restrict__ coef,
                                              const float* __restrict__ bias,
                                              __bf16* __restrict__ wbf,
                                              float* __restrict__ bterm) {
    long id = blockIdx.x;
    if (id < 4608) {                       // 1,179,648 threads: (o, r, cb-of-8c) each
        int e  = (int)id * 256 + threadIdx.x;
        int cb = e % 96;                   // c-block of 8
        int t2 = e / 96;
        int r  = t2 & 15;
        int o  = t2 >> 4;
        const float* wp = w + ((long)o * CC + cb * 8) * RR + r;   // stride RR gather
        bf16x8 v;
#pragma unroll
        for (int j = 0; j < 8; ++j) v[j] = (__bf16)wp[j * RR];
        *(bf16x8*)(wbf + (long)o * KK + r * CC + cb * 8) = v;     // contiguous 16B
    } else {                               // bias_term: 1024*768 dots of length 16
        int i = (int)(id - 4608) * 256 + threadIdx.x;
        int n = i / OO, o = i - n * OO;
        float4 c0 = *(const float4*)(coef + n * RR);
        float4 c1 = *(const float4*)(coef + n * RR + 4);
        float4 c2 = *(const float4*)(coef + n * RR + 8);
        float4 c3 = *(const float4*)(coef + n * RR + 12);
        float4 b0 = *(const float4*)(bias + o * RR);
        float4 b1 = *(const float4*)(bias + o * RR + 4);
        float4 b2 = *(const float4*)(bias + o * RR + 8);
        float4 b3 = *(const float4*)(bias + o * RR + 12);
        float s = c0.x*b0.x + c0.y*b0.y + c0.z*b0.z + c0.w*b0.w
                + c1.x*b1.x + c1.y*b1.y + c1.z*b1.z + c1.w*b1.w
                + c2.x*b2.x + c2.y*b2.y + c2.z*b2.z + c2.w*b2.w
                + c3.x*b3.x + c3.y*b3.y + c3.z*b3.z + c3.w*b3.w;
        bterm[i] = s;
    }
}

// ---- main GEMM, r-major k: out[m,o] = sum_{r,c} (coef[n,r]*x[m,c]) * W[o,c,r] + bterm ----
// A-frag (16x16x32: row=lane&15, k_local=quad*8+j) = coef[n,r] * x[row][cb*64+ks*32+quad*8+j]
// -> A never touches LDS; the lane's 16 x-values are register-resident for 16 k-tiles (all r).
// LDS holds only B, double-buffered; one barrier per k-tile.
__global__ __launch_bounds__(NTHR, 3) void k_gemm(const float* __restrict__ x,
                                                  const float* __restrict__ coef,
                                                  const __bf16* __restrict__ wbf,
                                                  const float* __restrict__ bterm,
                                                  float* __restrict__ out) {
    __shared__ __bf16 lB[2][BO * BK];   // 2 x 24 KB

    const int tid = threadIdx.x;

    // XCD swizzle: 2 XCDs per otile; all blocks of an XCD walk the SAME 24KB B-window
    // per k-tile in barrier-synced lockstep -> L2-resident B.
    int bid = blockIdx.x;
    int swz = (bid & 7) * (NBLK / 8) + (bid >> 3);
    const int otile = swz >> 6;      // 0..3
    const int mtile = swz & 63;      // 0..63
    const int m0 = mtile * BM, o0 = otile * BO;

    const int lane = tid & 63, wave = tid >> 6;     // 12 waves
    const int wr = wave & 3, wc = wave >> 2;        // 4m x 3o
    const int lrow = lane & 15, quad = lane >> 4;

    // ---- per-lane A state: 2 m-row-blocks ----
    const float* xq[2];
    const float* cq[2];
#pragma unroll
    for (int im = 0; im < 2; ++im) {
        int mg = m0 + wr * 32 + im * 16 + lrow;
        int n  = mg & (NN - 1);
        xq[im] = x + (long)mg * CC;
        cq[im] = coef + n * RR;
    }

    f32x2 xcur[2][8];      // lane's 16 x-values for current c-block (static idx only)
    float4 xnxt[2][4];     // next c-block, filled during r=12..15
    f32x4 acc[2][4] = {};

    // stage B-tile at k-offset koff into buffer b (async DMA, global-side XOR swizzle)
    auto STAGE = [&](int b, int koff) {
#pragma unroll
        for (int s = 0; s < 2; ++s) {
            int u = s * NTHR + tid;            // 1536 chunks of 16B
            int row = u >> 3, cl = u & 7;
            int g = cl ^ (row & 7);
            const __bf16* gp = wbf + (long)(o0 + row) * KK + koff + g * 8;
            gl_lds16(gp, ((char*)lB[b]) + u * 16);
        }
    };

    // ---- prologue: x-chunk for cb=0, stage tile (r=0, cb=0) ----
#pragma unroll
    for (int im = 0; im < 2; ++im)
#pragma unroll
        for (int p = 0; p < 4; ++p) {
            float4 v = *(const float4*)(xq[im] + (p >> 1) * 32 + quad * 8 + (p & 1) * 4);
            xcur[im][p * 2]     = mk2(v.x, v.y);
            xcur[im][p * 2 + 1] = mk2(v.z, v.w);
        }
    STAGE(0, 0);
    __syncthreads();

#pragma unroll 1
    for (int cb = 0; cb < CBLK; ++cb) {
#pragma unroll
        for (int r = 0; r < RBLK; ++r) {       // FULLY unrolled: all reg indices static
            const int cur = r & 1;
            // stage next k-tile (r+1, cb) or (0, cb+1)
            if (!(cb == CBLK - 1 && r == RBLK - 1)) {
                int koff = (r < RBLK - 1) ? ((r + 1) * CC + cb * BK) : ((cb + 1) * BK);
                STAGE(cur ^ 1, koff);
            }
            // per-row coef scalars for this r (L1-hot, 2 dwords)
            float cc0 = cq[0][r], cc1 = cq[1][r];
            // prefetch next c-block's x during the last 4 r-iterations
            if (r >= 12 && cb < CBLK - 1) {
                const int p = r - 12;
                xnxt[0][p] = *(const float4*)(xq[0] + (cb + 1) * BK + (p >> 1) * 32 + quad * 8 + (p & 1) * 4);
                xnxt[1][p] = *(const float4*)(xq[1] + (cb + 1) * BK + (p >> 1) * 32 + quad * 8 + (p & 1) * 4);
            }
            // ---- compute tile: 2 k-steps; A synthesized in regs, B from LDS ----
#pragma unroll
            for (int ks = 0; ks < 2; ++ks) {
                const int kb = ks * 4 + quad;
                bf16x8 bfr[4];
#pragma unroll
                for (int io = 0; io < 4; ++io) {
                    int brow = wc * 64 + io * 16 + lrow;
                    bfr[io] = *(const bf16x8*)(&lB[cur][brow * BK + ((kb ^ (brow & 7))) * 8]);
                }
#pragma unroll
                for (int im = 0; im < 2; ++im) {
                    const float ccv = im ? cc1 : cc0;
                    const f32x2 c2 = mk2(ccv, ccv);
                    bf16x8 af;
#pragma unroll
                    for (int h = 0; h < 4; ++h) {
                        f32x2 pr = xcur[im][ks * 4 + h] * c2;   // v_pk_mul_f32
                        af[2 * h]     = (__bf16)pr[0];
                        af[2 * h + 1] = (__bf16)pr[1];
                    }
#pragma unroll
                    for (int io = 0; io < 4; ++io)
                        acc[im][io] = __builtin_amdgcn_mfma_f32_16x16x32_bf16(
                            af, bfr[io], acc[im][io], 0, 0, 0);
                }
            }
            __syncthreads();   // single barrier/k-tile: drains next-tile DMA, guards buffers
        }
        // rotate x-chunk (static unrolled movs, once per 16 k-tiles)
        if (cb < CBLK - 1) {
#pragma unroll
            for (int im = 0; im < 2; ++im)
#pragma unroll
                for (int p = 0; p < 4; ++p) {
                    xcur[im][p * 2]     = mk2(xnxt[im][p].x, xnxt[im][p].y);
                    xcur[im][p * 2 + 1] = mk2(xnxt[im][p].z, xnxt[im][p].w);
                }
        }
    }

    // ---- epilogue: D col=lane&15 (o), row=quad*4+reg (m); add bias_term ----
#pragma unroll
    for (int im = 0; im < 2; ++im) {
#pragma unroll
        for (int io = 0; io < 4; ++io) {
            int o = o0 + wc * 64 + io * 16 + lrow;
#pragma unroll
            for (int rr2 = 0; rr2 < 4; ++rr2) {
                int moff = wr * 32 + im * 16 + quad * 4 + rr2;
                long m = m0 + moff;
                int n = (int)(m & (NN - 1));
                out[m * OO + o] = acc[im][io][rr2] + bterm[(long)n * OO + o];
            }
        }
    }
}

// ---- fallback if workspace too small (correctness-only) ----
__global__ void k_naive(const float* __restrict__ x, const float* __restrict__ coef,
                        const float* __restrict__ w, const float* __restrict__ bias,
                        float* __restrict__ out) {
    long i = (long)blockIdx.x * 256 + threadIdx.x;
    if (i >= (long)MM * OO) return;
    int o = (int)(i % OO);
    long m = i / OO;
    int n = (int)(m & (NN - 1));
    float cf[16];
#pragma unroll
    for (int r = 0; r < 16; ++r) cf[r] = coef[n * RR + r];
    const float* xr = x + m * CC;
    const float* wr = w + (long)o * CC * RR;
    float s = 0.f;
    for (int c = 0; c < CC; ++c) {
        float t = 0.f;
#pragma unroll
        for (int r = 0; r < 16; ++r) t += cf[r] * wr[c * RR + r];
        s += xr[c] * t;
    }
    float bs = 0.f;
#pragma unroll
    for (int r = 0; r < 16; ++r) bs += cf[r] * bias[o * RR + r];
    out[i] = s + bs;
}

extern "C" void kernel_launch(void* const* d_in, const int* in_sizes, int n_in,
                              void* d_out, int out_size, void* d_ws, size_t ws_size,
                              hipStream_t stream) {
    const float* x    = (const float*)d_in[0];
    const float* coef = (const float*)d_in[1];
    const float* w    = (const float*)d_in[2];
    const float* bias = (const float*)d_in[3];
    float* out = (float*)d_out;

    const size_t wbf_bytes = (size_t)OO * KK * sizeof(__bf16);   // 18,874,368
    const size_t bt_bytes  = (size_t)NN * OO * sizeof(float);    //  3,145,728

    if (ws_size >= wbf_bytes + bt_bytes) {
        __bf16* wbf  = (__bf16*)d_ws;
        float*  btrm = (float*)((char*)d_ws + wbf_bytes);
        k_prep<<<7680, 256, 0, stream>>>(w, coef, bias, wbf, btrm);
        k_gemm<<<NBLK, NTHR, 0, stream>>>(x, coef, wbf, btrm, out);
    } else {
        k_naive<<<(int)(((long)MM * OO + 255) / 256), 256, 0, stream>>>(x, coef, w, bias, out);
    }
}